// Round 1
// baseline (211.124 us; speedup 1.0000x reference)
//
#include <hip/hip_runtime.h>
#include <hip/hip_bf16.h>

// out = spline(x) @ proj_w^T + x @ res_w^T + proj_b
// x: (16384, 1024) f32.  A_bf16 = [spline(x) | x] : (16384, 2048)
// Bcat_bf16 = [proj_w | res_w] : (1024, 2048)  (K-contiguous, "B^T" GEMM)

#define IN_F   1024
#define OUT_F  1024
#define KNOTS  12
#define M_ROWS 16384
#define GK     2048

#define BM 128
#define BN 128
#define BK 32

typedef __attribute__((ext_vector_type(8))) __bf16 bf16x8;
typedef __attribute__((ext_vector_type(4))) float  f32x4;

__device__ __forceinline__ unsigned short f2bf(float v) {
    unsigned int u = __float_as_uint(v);
    u = (u + 0x7fffu + ((u >> 16) & 1u)) >> 16;   // RNE
    return (unsigned short)u;
}

__device__ __forceinline__ void gload16(const void* g, void* l) {
    __builtin_amdgcn_global_load_lds(
        (const __attribute__((address_space(1))) void*)g,
        (__attribute__((address_space(3))) void*)l, 16, 0, 0);
}

// ---------------- prep: sort knots, fold sigmoid, precompute tables ----------
__global__ __launch_bounds__(256) void prep_kernel(
    const float* __restrict__ grid, const float* __restrict__ coeffs,
    const float* __restrict__ tangents, const float* __restrict__ alive,
    float* __restrict__ gmin, float* __restrict__ gmax, float* __restrict__ scale,
    float* __restrict__ mc, float* __restrict__ md0, float* __restrict__ md1)
{
    int f = blockIdx.x * blockDim.x + threadIdx.x;
    if (f >= IN_F) return;
    float g[KNOTS], c[KNOTS], t[KNOTS], a[KNOTS];
    for (int i = 0; i < KNOTS; ++i) {
        g[i] = grid[f*KNOTS+i];  c[i] = coeffs[f*KNOTS+i];
        t[i] = tangents[f*KNOTS+i]; a[i] = alive[f*KNOTS+i];
    }
    // stable insertion sort by g (matches jnp.argsort stable)
    for (int i = 1; i < KNOTS; ++i) {
        float gk=g[i], ck=c[i], tk=t[i], ak=a[i];
        int j = i-1;
        while (j >= 0 && g[j] > gk) { g[j+1]=g[j]; c[j+1]=c[j]; t[j+1]=t[j]; a[j+1]=a[j]; --j; }
        g[j+1]=gk; c[j+1]=ck; t[j+1]=tk; a[j+1]=ak;
    }
    float mcl[KNOTS], mtl[KNOTS];
    for (int i = 0; i < KNOTS; ++i) {
        float s = 1.f / (1.f + expf(-a[i]));
        mcl[i] = c[i]*s;  mtl[i] = t[i]*s;
    }
    gmin[f] = g[0];  gmax[f] = g[KNOTS-1];
    float grange = fmaxf(g[KNOTS-1] - g[0], 1e-6f);
    scale[f] = (float)(KNOTS-1) / grange;
    for (int i = 0; i < KNOTS; ++i) mc[f*KNOTS+i] = mcl[i];
    for (int i = 0; i < KNOTS-1; ++i) {
        float dx = fmaxf(g[i+1]-g[i], 1e-6f);
        md0[f*KNOTS+i] = mtl[i]*dx;
        md1[f*KNOTS+i] = mtl[i+1]*dx;
    }
    md0[f*KNOTS+KNOTS-1] = 0.f;  md1[f*KNOTS+KNOTS-1] = 0.f;
}

__device__ __forceinline__ float eval_spline(float xi, int f,
    const float* __restrict__ gmin, const float* __restrict__ gmax,
    const float* __restrict__ scale, const float* __restrict__ mc,
    const float* __restrict__ md0, const float* __restrict__ md1)
{
    float gm = gmin[f], gM = gmax[f];
    float xc = fminf(fmaxf(xi, gm), gM);
    float xn = (xc - gm) * scale[f];
    int idx = (int)xn;  idx = idx < (KNOTS-2) ? idx : (KNOTS-2);
    float tt = xn - (float)idx;
    float t2 = tt*tt, t3 = t2*tt;
    float h00 = 2.f*t3 - 3.f*t2 + 1.f;
    float h01 = -2.f*t3 + 3.f*t2;
    float h10 = t3 - 2.f*t2 + tt;
    float h11 = t3 - t2;
    int b = f*KNOTS + idx;
    return h00*mc[b] + h01*mc[b+1] + h10*md0[b] + h11*md1[b];
}

// ---------------- spline + cast:  A = [spline(x) | x]  bf16 -----------------
__global__ __launch_bounds__(256) void spline_kernel(const float* __restrict__ x,
    const float* __restrict__ gmin, const float* __restrict__ gmax,
    const float* __restrict__ scale, const float* __restrict__ mc,
    const float* __restrict__ md0, const float* __restrict__ md1,
    unsigned short* __restrict__ A)
{
    int row = blockIdx.x;
    int f0  = threadIdx.x * 4;
    float4 xv = *reinterpret_cast<const float4*>(x + (size_t)row*IN_F + f0);
    float xs[4] = {xv.x, xv.y, xv.z, xv.w};
    ushort4 so, xo;
    unsigned short* sp = (unsigned short*)&so;
    unsigned short* xp = (unsigned short*)&xo;
    #pragma unroll
    for (int j = 0; j < 4; ++j) {
        sp[j] = f2bf(eval_spline(xs[j], f0+j, gmin, gmax, scale, mc, md0, md1));
        xp[j] = f2bf(xs[j]);
    }
    size_t base = (size_t)row * GK;
    *reinterpret_cast<ushort4*>(A + base + f0)          = so;
    *reinterpret_cast<ushort4*>(A + base + IN_F + f0)   = xo;
}

// ---------------- B cast: Bcat = [proj_w | res_w] bf16 ----------------------
__global__ __launch_bounds__(256) void bcast_kernel(
    const float* __restrict__ P, const float* __restrict__ R,
    unsigned short* __restrict__ Bc)
{
    int g = blockIdx.x*256 + threadIdx.x;          // OUT_F*GK/4 total
    int n  = g >> 9;
    int k4 = (g & 511) * 4;
    const float* src = (k4 < IN_F) ? (P + (size_t)n*IN_F + k4)
                                   : (R + (size_t)n*IN_F + (k4 - IN_F));
    float4 v = *reinterpret_cast<const float4*>(src);
    ushort4 o;
    o.x = f2bf(v.x); o.y = f2bf(v.y); o.z = f2bf(v.z); o.w = f2bf(v.w);
    *reinterpret_cast<ushort4*>(Bc + (size_t)n*GK + k4) = o;
}

// ---------------- GEMM: C = A @ Bcat^T + bias (m97 structure) ---------------
__global__ __launch_bounds__(256) void gemm_kernel(
    const unsigned short* __restrict__ A, const unsigned short* __restrict__ B,
    const float* __restrict__ bias, float* __restrict__ C)
{
    __shared__ unsigned short sA[BM*BK];
    __shared__ unsigned short sB[BN*BK];
    const int tid  = threadIdx.x;
    const int bx   = blockIdx.x;   // N tiles: 8
    const int by   = blockIdx.y;   // M tiles: 128
    const int lane = tid & 63;
    const int wave = tid >> 6;
    const int wr = wave >> 1, wc = wave & 1;

    const int srow = tid >> 2;            // 0..63
    const int sk8  = (tid & 3) * 8;       // 0,8,16,24

    const size_t aBase = (size_t)by * BM * GK;
    const size_t bBase = (size_t)bx * BN * GK;

    const int lr = lane & 15;
    const int lk = (lane >> 4) * 8;

    f32x4 acc[4][4] = {};

    for (int k0 = 0; k0 < GK; k0 += BK) {
        gload16(A + aBase + (size_t)srow      *GK + k0 + sk8, &sA[(size_t)tid*8]);
        gload16(A + aBase + (size_t)(srow+64) *GK + k0 + sk8, &sA[(size_t)(tid+256)*8]);
        gload16(B + bBase + (size_t)srow      *GK + k0 + sk8, &sB[(size_t)tid*8]);
        gload16(B + bBase + (size_t)(srow+64) *GK + k0 + sk8, &sB[(size_t)(tid+256)*8]);
        __syncthreads();   // compiler drains vmcnt before barrier

        bf16x8 af[4], bb[4];
        #pragma unroll
        for (int m = 0; m < 4; ++m)
            af[m] = *reinterpret_cast<const bf16x8*>(&sA[(wr*64 + m*16 + lr)*BK + lk]);
        #pragma unroll
        for (int n = 0; n < 4; ++n)
            bb[n] = *reinterpret_cast<const bf16x8*>(&sB[(wc*64 + n*16 + lr)*BK + lk]);
        #pragma unroll
        for (int m = 0; m < 4; ++m)
            #pragma unroll
            for (int n = 0; n < 4; ++n)
                acc[m][n] = __builtin_amdgcn_mfma_f32_16x16x32_bf16(af[m], bb[n], acc[m][n], 0, 0, 0);
        __syncthreads();
    }

    const int r0 = (lane >> 4) * 4;
    #pragma unroll
    for (int n = 0; n < 4; ++n) {
        int col = bx*BN + wc*64 + n*16 + lr;
        float bv = bias[col];
        #pragma unroll
        for (int m = 0; m < 4; ++m) {
            int grow = by*BM + wr*64 + m*16 + r0;
            #pragma unroll
            for (int r = 0; r < 4; ++r)
                C[(size_t)(grow + r)*OUT_F + col] = acc[m][n][r] + bv;
        }
    }
}

// ---------------- fallback (ws too small): fused fp32, slow but correct -----
__global__ __launch_bounds__(256) void fallback_kernel(
    const float* __restrict__ x, const float* __restrict__ P,
    const float* __restrict__ R, const float* __restrict__ pb,
    const float* __restrict__ gmin, const float* __restrict__ gmax,
    const float* __restrict__ scale, const float* __restrict__ mc,
    const float* __restrict__ md0, const float* __restrict__ md1,
    float* __restrict__ out)
{
    __shared__ float s_s[IN_F];
    __shared__ float s_x[IN_F];
    int row = blockIdx.x;
    const float* xr = x + (size_t)row*IN_F;
    for (int f = threadIdx.x; f < IN_F; f += 256) {
        float xi = xr[f];
        s_s[f] = eval_spline(xi, f, gmin, gmax, scale, mc, md0, md1);
        s_x[f] = xi;
    }
    __syncthreads();
    for (int j = 0; j < 4; ++j) {
        int o = threadIdx.x + j*256;
        const float* Pr = P + (size_t)o*IN_F;
        const float* Rr = R + (size_t)o*IN_F;
        float acc = pb[o];
        for (int f = 0; f < IN_F; ++f)
            acc = fmaf(s_s[f], Pr[f], fmaf(s_x[f], Rr[f], acc));
        out[(size_t)row*OUT_F + o] = acc;
    }
}

extern "C" void kernel_launch(void* const* d_in, const int* in_sizes, int n_in,
                              void* d_out, int out_size, void* d_ws, size_t ws_size,
                              hipStream_t stream) {
    const float* x         = (const float*)d_in[0];
    const float* grid      = (const float*)d_in[1];
    const float* coeffs    = (const float*)d_in[2];
    const float* tangents  = (const float*)d_in[3];
    const float* knotalive = (const float*)d_in[4];
    const float* proj_w    = (const float*)d_in[5];
    const float* proj_b    = (const float*)d_in[6];
    const float* res_w     = (const float*)d_in[7];
    float* out = (float*)d_out;

    const size_t needB  = (size_t)OUT_F * GK * 2;     // 4 MiB
    const size_t needA  = (size_t)M_ROWS * GK * 2;    // 64 MiB
    const size_t tabF   = (size_t)IN_F*3 + (size_t)IN_F*KNOTS*3;  // floats
    const size_t needT  = tabF * 4;

    char* ws = (char*)d_ws;
    if (ws_size >= needB + needA + needT) {
        unsigned short* Bcat = (unsigned short*)ws;
        unsigned short* Abuf = (unsigned short*)(ws + needB);
        float* tab  = (float*)(ws + needB + needA);
        float* gmin = tab;
        float* gmax = tab + IN_F;
        float* scl  = tab + 2*IN_F;
        float* mc   = tab + 3*IN_F;
        float* md0  = mc + IN_F*KNOTS;
        float* md1  = md0 + IN_F*KNOTS;

        prep_kernel<<<(IN_F+255)/256, 256, 0, stream>>>(grid, coeffs, tangents, knotalive,
                                                        gmin, gmax, scl, mc, md0, md1);
        bcast_kernel<<<(OUT_F*GK/4)/256, 256, 0, stream>>>(proj_w, res_w, Bcat);
        spline_kernel<<<M_ROWS, 256, 0, stream>>>(x, gmin, gmax, scl, mc, md0, md1, Abuf);
        dim3 gg(OUT_F/BN, M_ROWS/BM);
        gemm_kernel<<<gg, 256, 0, stream>>>(Abuf, Bcat, proj_b, out);
    } else {
        float* tab  = (float*)ws;
        float* gmin = tab;
        float* gmax = tab + IN_F;
        float* scl  = tab + 2*IN_F;
        float* mc   = tab + 3*IN_F;
        float* md0  = mc + IN_F*KNOTS;
        float* md1  = md0 + IN_F*KNOTS;
        prep_kernel<<<(IN_F+255)/256, 256, 0, stream>>>(grid, coeffs, tangents, knotalive,
                                                        gmin, gmax, scl, mc, md0, md1);
        fallback_kernel<<<M_ROWS, 256, 0, stream>>>(x, proj_w, res_w, proj_b,
                                                    gmin, gmax, scl, mc, md0, md1, out);
    }
}

// Round 2
// 112.137 us; speedup vs baseline: 1.8827x; 1.8827x over previous
//
#include <hip/hip_runtime.h>
#include <hip/hip_bf16.h>

// out = spline(x) @ proj_w^T + x @ res_w^T + proj_b
// A_bf16 = [spline(x) | x] : (16384, 2048),  Bcat_bf16 = [proj_w | res_w] : (1024, 2048)

#define IN_F   1024
#define OUT_F  1024
#define KNOTS  12
#define M_ROWS 16384
#define GK     2048

// ---- GEMM params: 256x256 tile, BK=32, 8 waves, 4-deep LDS pipeline ----
#define BM   256
#define BN   256
#define BKT  32
#define NT   (GK / BKT)     // 64 K-tiles
#define NBUF 4

typedef __attribute__((ext_vector_type(8))) __bf16 bf16x8;
typedef __attribute__((ext_vector_type(4))) float  f32x4;

__device__ __forceinline__ unsigned short f2bf(float v) {
    unsigned int u = __float_as_uint(v);
    u = (u + 0x7fffu + ((u >> 16) & 1u)) >> 16;   // RNE
    return (unsigned short)u;
}

__device__ __forceinline__ void gload16(const void* g, void* l) {
    __builtin_amdgcn_global_load_lds(
        (const __attribute__((address_space(1))) void*)g,
        (__attribute__((address_space(3))) void*)l, 16, 0, 0);
}

// ---------------- prep: sort knots, fold sigmoid, build float4 Hermite table
// H[f][k] = { mc[k], mc[k+1], mt[k]*dx_k, mt[k+1]*dx_k },  k = 0..10
__global__ __launch_bounds__(256) void prep_kernel(
    const float* __restrict__ grid, const float* __restrict__ coeffs,
    const float* __restrict__ tangents, const float* __restrict__ alive,
    float* __restrict__ gmin, float* __restrict__ scale, float4* __restrict__ H)
{
    int f = blockIdx.x * blockDim.x + threadIdx.x;
    if (f >= IN_F) return;
    float g[KNOTS], c[KNOTS], t[KNOTS], a[KNOTS];
    for (int i = 0; i < KNOTS; ++i) {
        g[i] = grid[f*KNOTS+i];  c[i] = coeffs[f*KNOTS+i];
        t[i] = tangents[f*KNOTS+i]; a[i] = alive[f*KNOTS+i];
    }
    for (int i = 1; i < KNOTS; ++i) {       // stable insertion sort on g
        float gk=g[i], ck=c[i], tk=t[i], ak=a[i];
        int j = i-1;
        while (j >= 0 && g[j] > gk) { g[j+1]=g[j]; c[j+1]=c[j]; t[j+1]=t[j]; a[j+1]=a[j]; --j; }
        g[j+1]=gk; c[j+1]=ck; t[j+1]=tk; a[j+1]=ak;
    }
    float mcl[KNOTS], mtl[KNOTS];
    for (int i = 0; i < KNOTS; ++i) {
        float s = 1.f / (1.f + expf(-a[i]));
        mcl[i] = c[i]*s;  mtl[i] = t[i]*s;
    }
    gmin[f] = g[0];
    float grange = fmaxf(g[KNOTS-1] - g[0], 1e-6f);
    scale[f] = (float)(KNOTS-1) / grange;
    for (int k = 0; k < KNOTS-1; ++k) {
        float dx = fmaxf(g[k+1]-g[k], 1e-6f);
        H[(size_t)f*KNOTS + k] = make_float4(mcl[k], mcl[k+1], mtl[k]*dx, mtl[k+1]*dx);
    }
    H[(size_t)f*KNOTS + KNOTS-1] = make_float4(0.f, 0.f, 0.f, 0.f);
}

// ---------------- spline + cast:  A = [spline(x) | x]  bf16 -----------------
// block = 256 threads = 256 features; tables in LDS; loop 64 rows.
#define SROWS 64
#define HPAD  13   // pad stride 12->13 float4 to spread LDS banks
__global__ __launch_bounds__(256) void spline_kernel(const float* __restrict__ x,
    const float* __restrict__ gmin, const float* __restrict__ scale,
    const float4* __restrict__ H, unsigned short* __restrict__ A)
{
    __shared__ float4 sH[256 * HPAD];     // 52 KiB
    const int tid = threadIdx.x;
    const int f   = blockIdx.y * 256 + tid;
    #pragma unroll
    for (int k = 0; k < KNOTS; ++k) sH[tid*HPAD + k] = H[(size_t)f*KNOTS + k];
    const float gm = gmin[f];
    const float sc = scale[f];
    __syncthreads();
    const int r0 = blockIdx.x * SROWS;
    #pragma unroll 4
    for (int r = 0; r < SROWS; ++r) {
        const int row = r0 + r;
        const float xi = x[(size_t)row*IN_F + f];
        float xn = (xi - gm) * sc;
        xn = fminf(fmaxf(xn, 0.f), (float)(KNOTS-1));
        int idx = (int)xn;  idx = idx > (KNOTS-2) ? (KNOTS-2) : idx;
        const float tt = xn - (float)idx;
        const float4 h = sH[tid*HPAD + idx];
        const float t2 = tt*tt, t3 = t2*tt;
        const float h00 =  2.f*t3 - 3.f*t2 + 1.f;
        const float h01 = -2.f*t3 + 3.f*t2;
        const float h10 =  t3 - 2.f*t2 + tt;
        const float h11 =  t3 - t2;
        const float sv  = h00*h.x + h01*h.y + h10*h.z + h11*h.w;
        const size_t base = (size_t)row * GK;
        A[base + f]        = f2bf(sv);
        A[base + IN_F + f] = f2bf(xi);
    }
}

// ---------------- B cast: Bcat = [proj_w | res_w] bf16 ----------------------
__global__ __launch_bounds__(256) void bcast_kernel(
    const float* __restrict__ P, const float* __restrict__ R,
    unsigned short* __restrict__ Bc)
{
    int g = blockIdx.x*256 + threadIdx.x;          // OUT_F*GK/4 total
    int n  = g >> 9;
    int k4 = (g & 511) * 4;
    const float* src = (k4 < IN_F) ? (P + (size_t)n*IN_F + k4)
                                   : (R + (size_t)n*IN_F + (k4 - IN_F));
    float4 v = *reinterpret_cast<const float4*>(src);
    ushort4 o;
    o.x = f2bf(v.x); o.y = f2bf(v.y); o.z = f2bf(v.z); o.w = f2bf(v.w);
    *reinterpret_cast<ushort4*>(Bc + (size_t)n*GK + k4) = o;
}

// ---------------- GEMM: C = A @ Bcat^T + bias ------------------------------
// 256x256 tile, BK=32, 512 threads (8 waves: 2M x 4N, each 128x64 out).
// 4-deep circular LDS buffer; stage tile t+3 during tile t; counted vmcnt(8);
// raw s_barrier; XOR swizzle (c ^= (row>>1)&3) applied on global source AND
// on ds_read (involution, rule 21); setprio around MFMA clusters.
__global__ __launch_bounds__(512, 2) void gemm_kernel(
    const unsigned short* __restrict__ A, const unsigned short* __restrict__ B,
    const float* __restrict__ bias, float* __restrict__ C)
{
    __shared__ unsigned short sA[NBUF][BM*BKT];   // 4 x 16 KiB
    __shared__ unsigned short sB[NBUF][BN*BKT];   // 4 x 16 KiB  => 128 KiB total

    const int tid  = threadIdx.x;
    // XCD-bijective swizzle: 256 wgs, 8 XCDs, 32 per chunk
    const int wg   = blockIdx.x;
    const int swz  = (wg & 7) * 32 + (wg >> 3);
    const int by   = swz >> 2;         // 0..63  M-tile
    const int bx   = swz & 3;          // 0..3   N-tile

    const int lane = tid & 63;
    const int wave = tid >> 6;         // 0..7
    const int wr   = wave >> 2;        // 0..1  M-wave (128 rows)
    const int wc   = wave & 3;         // 0..3  N-wave (64 cols)
    const int lr   = lane & 15;
    const int bsel = lane >> 4;        // 16B block within 64B row

    const size_t aBase = (size_t)by * BM * GK;
    const size_t bBase = (size_t)bx * BN * GK;

    f32x4 acc[8][4] = {};

    auto stageA = [&](int t, int buf) {
        const int k0 = t * BKT;
        #pragma unroll
        for (int i = 0; i < 2; ++i) {
            const int L = i*512 + tid;
            const int row = L >> 2, c = L & 3;
            const int cs = c ^ ((row >> 1) & 3);
            gload16(A + aBase + (size_t)row*GK + k0 + cs*8, &sA[buf][(size_t)L*8]);
        }
    };
    auto stageB = [&](int t, int buf) {
        const int k0 = t * BKT;
        #pragma unroll
        for (int i = 0; i < 2; ++i) {
            const int L = i*512 + tid;
            const int row = L >> 2, c = L & 3;
            const int cs = c ^ ((row >> 1) & 3);
            gload16(B + bBase + (size_t)row*GK + k0 + cs*8, &sB[buf][(size_t)L*8]);
        }
    };
    auto ldA = [&](int buf, int row) -> bf16x8 {
        const int cs = bsel ^ ((row >> 1) & 3);
        return *reinterpret_cast<const bf16x8*>(&sA[buf][row*BKT + cs*8]);
    };
    auto ldB = [&](int buf, int row) -> bf16x8 {
        const int cs = bsel ^ ((row >> 1) & 3);
        return *reinterpret_cast<const bf16x8*>(&sB[buf][row*BKT + cs*8]);
    };

    // prologue: stage tiles 0,1,2  (12 loads in flight)
    stageA(0,0); stageB(0,0);
    stageA(1,1); stageB(1,1);
    stageA(2,2); stageB(2,2);

    for (int t = 0; t < NT; ++t) {
        const int buf = t & 3;
        // ---- phase 1 ----
        if (t < NT-2)        asm volatile("s_waitcnt vmcnt(8)" ::: "memory");
        else if (t == NT-2)  asm volatile("s_waitcnt vmcnt(4)" ::: "memory");
        else                 asm volatile("s_waitcnt vmcnt(0)" ::: "memory");
        __builtin_amdgcn_s_barrier();

        bf16x8 a0[4], bfr[4];
        #pragma unroll
        for (int m = 0; m < 4; ++m) a0[m] = ldA(buf, wr*128 + m*16 + lr);
        #pragma unroll
        for (int n = 0; n < 4; ++n) bfr[n] = ldB(buf, wc*64 + n*16 + lr);
        if (t + 3 < NT) stageA(t+3, (t+3) & 3);
        __builtin_amdgcn_sched_barrier(0);
        __builtin_amdgcn_s_barrier();

        __builtin_amdgcn_s_setprio(1);
        #pragma unroll
        for (int m = 0; m < 4; ++m)
            #pragma unroll
            for (int n = 0; n < 4; ++n)
                acc[m][n] = __builtin_amdgcn_mfma_f32_16x16x32_bf16(a0[m], bfr[n], acc[m][n], 0, 0, 0);
        __builtin_amdgcn_s_setprio(0);

        // ---- phase 2 ----
        bf16x8 a1[4];
        #pragma unroll
        for (int m = 0; m < 4; ++m) a1[m] = ldA(buf, wr*128 + 64 + m*16 + lr);
        if (t + 3 < NT) stageB(t+3, (t+3) & 3);
        __builtin_amdgcn_sched_barrier(0);
        __builtin_amdgcn_s_barrier();

        __builtin_amdgcn_s_setprio(1);
        #pragma unroll
        for (int m = 0; m < 4; ++m)
            #pragma unroll
            for (int n = 0; n < 4; ++n)
                acc[4+m][n] = __builtin_amdgcn_mfma_f32_16x16x32_bf16(a1[m], bfr[n], acc[4+m][n], 0, 0, 0);
        __builtin_amdgcn_s_setprio(0);
    }

    // epilogue: C = acc + bias   (C/D map: col = lane&15, row = (lane>>4)*4 + r)
    const int r0 = (lane >> 4) * 4;
    #pragma unroll
    for (int n = 0; n < 4; ++n) {
        const int col = bx*BN + wc*64 + n*16 + lr;
        const float bv = bias[col];
        #pragma unroll
        for (int m = 0; m < 8; ++m) {
            const int grow = by*BM + wr*128 + m*16 + r0;
            #pragma unroll
            for (int r = 0; r < 4; ++r)
                C[(size_t)(grow + r)*OUT_F + col] = acc[m][n][r] + bv;
        }
    }
}

// ---------------- fallback (ws too small): fused fp32, slow but correct -----
__global__ __launch_bounds__(256) void fallback_kernel(
    const float* __restrict__ x, const float* __restrict__ P,
    const float* __restrict__ R, const float* __restrict__ pb,
    const float* __restrict__ gmin, const float* __restrict__ scale,
    const float4* __restrict__ H, float* __restrict__ out)
{
    __shared__ float s_s[IN_F];
    __shared__ float s_x[IN_F];
    int row = blockIdx.x;
    const float* xr = x + (size_t)row*IN_F;
    for (int f = threadIdx.x; f < IN_F; f += 256) {
        float xi = xr[f];
        float xn = (xi - gmin[f]) * scale[f];
        xn = fminf(fmaxf(xn, 0.f), (float)(KNOTS-1));
        int idx = (int)xn;  idx = idx > (KNOTS-2) ? (KNOTS-2) : idx;
        float tt = xn - (float)idx;
        float4 h = H[(size_t)f*KNOTS + idx];
        float t2 = tt*tt, t3 = t2*tt;
        s_s[f] = (2.f*t3-3.f*t2+1.f)*h.x + (-2.f*t3+3.f*t2)*h.y
               + (t3-2.f*t2+tt)*h.z + (t3-t2)*h.w;
        s_x[f] = xi;
    }
    __syncthreads();
    for (int j = 0; j < 4; ++j) {
        int o = threadIdx.x + j*256;
        const float* Pr = P + (size_t)o*IN_F;
        const float* Rr = R + (size_t)o*IN_F;
        float acc = pb[o];
        for (int f = 0; f < IN_F; ++f)
            acc = fmaf(s_s[f], Pr[f], fmaf(s_x[f], Rr[f], acc));
        out[(size_t)row*OUT_F + o] = acc;
    }
}

extern "C" void kernel_launch(void* const* d_in, const int* in_sizes, int n_in,
                              void* d_out, int out_size, void* d_ws, size_t ws_size,
                              hipStream_t stream) {
    const float* x         = (const float*)d_in[0];
    const float* grid      = (const float*)d_in[1];
    const float* coeffs    = (const float*)d_in[2];
    const float* tangents  = (const float*)d_in[3];
    const float* knotalive = (const float*)d_in[4];
    const float* proj_w    = (const float*)d_in[5];
    const float* proj_b    = (const float*)d_in[6];
    const float* res_w     = (const float*)d_in[7];
    float* out = (float*)d_out;

    const size_t needB  = (size_t)OUT_F * GK * 2;                 // 4 MiB
    const size_t needA  = (size_t)M_ROWS * GK * 2;                // 64 MiB
    const size_t needT  = ((size_t)IN_F*2 + (size_t)IN_F*KNOTS*4) * 4;  // gmin+scale+H

    char* ws = (char*)d_ws;
    if (ws_size >= needB + needA + needT) {
        unsigned short* Bcat = (unsigned short*)ws;
        unsigned short* Abuf = (unsigned short*)(ws + needB);
        float*  gmin = (float*)(ws + needB + needA);
        float*  scl  = gmin + IN_F;
        float4* H    = (float4*)(scl + IN_F);

        prep_kernel<<<(IN_F+255)/256, 256, 0, stream>>>(grid, coeffs, tangents, knotalive,
                                                        gmin, scl, H);
        bcast_kernel<<<(OUT_F*GK/4)/256, 256, 0, stream>>>(proj_w, res_w, Bcat);
        spline_kernel<<<dim3(M_ROWS/SROWS, IN_F/256), 256, 0, stream>>>(x, gmin, scl, H, Abuf);
        gemm_kernel<<<(M_ROWS/BM)*(OUT_F/BN), 512, 0, stream>>>(Abuf, Bcat, proj_b, out);
    } else {
        float*  gmin = (float*)ws;
        float*  scl  = gmin + IN_F;
        float4* H    = (float4*)(scl + IN_F);
        prep_kernel<<<(IN_F+255)/256, 256, 0, stream>>>(grid, coeffs, tangents, knotalive,
                                                        gmin, scl, H);
        fallback_kernel<<<M_ROWS, 256, 0, stream>>>(x, proj_w, res_w, proj_b,
                                                    gmin, scl, H, out);
    }
}